// Round 3
// baseline (71.871 us; speedup 1.0000x reference)
//
#include <hip/hip_runtime.h>
#include <hip/hip_bf16.h>
#include <stdint.h>

#define IN_DIM  1024
#define LOW     128
#define OUT_DIM 1024
#define BATCH   8
#define SEQ     2048

typedef unsigned short u16;
typedef short bf16x8 __attribute__((ext_vector_type(8)));
typedef unsigned short u16x4 __attribute__((ext_vector_type(4)));
typedef float f32x4 __attribute__((ext_vector_type(4)));

__device__ __forceinline__ u16 f2bf(float f) {
    union { float f; uint32_t u; } v;
    v.f = f;
    uint32_t u = v.u;
    return (u16)((u + 0x7fffu + ((u >> 16) & 1u)) >> 16);
}

// ---------------------------------------------------------------------------
// gen_w: unified hyper-weight generation, T14 async-split + LDS double-buffer.
//   D half (bid<1024):  DgT[b][l][d] = dot(Dm[d*128+l][:], k[b][:])
//   U half (bid>=1024): UgT[b][o][l] = dot(Um[l*1024+o][:], k[b][:])
// Block tile: 16 m x 8 n = 128 rows (64 KB), as 8 chunks of 16 rows (8 KB).
// Pipeline per chunk: issue next-chunk global loads -> compute current from
// LDS -> write next chunk to other LDS buffer -> one barrier.
// grid 2048, LDS 18 KB -> 8 blocks/CU.
// ---------------------------------------------------------------------------
__global__ __launch_bounds__(256) void gen_w(const float* __restrict__ Dm,
                                             const float* __restrict__ Um,
                                             const float* __restrict__ kv,
                                             u16* __restrict__ DgT,
                                             u16* __restrict__ UgT) {
    __shared__ float stage[2][16 * 128];       // 2 x 8 KB
    __shared__ u16 tb[BATCH * 8 * 16];         // 2 KB transpose buffer

    int t = threadIdx.x;
    int bid = blockIdx.x;
    bool isU = bid >= 1024;
    int rb = isU ? (bid - 1024) : bid;
    const float* src = isU ? Um : Dm;
    u16* outp = isU ? UgT : DgT;
    int NTOT = isU ? 1024 : 128;   // minor dim total == p row-stride
    int MTOT = isU ? 128 : 1024;   // major dim total (contiguous output run)
    int sh = isU ? 7 : 4;
    int m0 = (rb >> sh) * 16;
    int n0 = (rb & ((1 << sh) - 1)) * 8;

    // ---- staging map (chunk-invariant). i=0: rows 0..7, i=1: rows 8..15
    int rs0 = t >> 5, c0 = t & 31;       // rs0 in 0..7
    int rs1 = rs0 + 8;
    int qs0 = c0 >> 3, j4s0 = c0 & 7;
    int cp0 = (qs0 << 3) | (j4s0 ^ (((qs0 << 1) ^ (rs0 & 7)) & 7));
    int cp1 = (qs0 << 3) | (j4s0 ^ (((qs0 << 1) ^ (rs1 & 7)) & 7));
    int so0 = rs0 * 128 + cp0 * 4;
    int so1 = rs1 * 128 + cp1 * 4;
    // global: chunk ch covers m = m0+2ch (+0 for rs0..7, +1 for rs1..15)
    const float* g0 = src + ((size_t)(m0 + 0) * NTOT + n0 + (rs0 & 7)) * 128 + c0 * 4;
    const float* g1 = src + ((size_t)(m0 + 1) * NTOT + n0 + (rs1 & 7)) * 128 + c0 * 4;
    size_t gstride = (size_t)2 * NTOT * 128;   // floats per chunk step

    // ---- compute map (chunk-invariant)
    int r  = t >> 4;          // chunk-local row 0..15
    int bp = (t >> 2) & 3;    // batch pair 0..3
    int q  = t & 3;           // quarter 0..3
    int sw = ((q << 1) ^ (r & 7)) & 7;

    // k slices in registers: batches 2bp, 2bp+1, quarter q (8 f32x4 each)
    f32x4 kr0[8], kr1[8];
#pragma unroll
    for (int j4 = 0; j4 < 8; ++j4) {
        kr0[j4] = *(const f32x4*)(kv + (2 * bp)     * LOW + q * 32 + j4 * 4);
        kr1[j4] = *(const f32x4*)(kv + (2 * bp + 1) * LOW + q * 32 + j4 * 4);
    }

    // ---- prologue: stage chunk 0
    f32x4 v0 = *(const f32x4*)g0;
    f32x4 v1 = *(const f32x4*)g1;
    *(f32x4*)(stage[0] + so0) = v0;
    *(f32x4*)(stage[0] + so1) = v1;
    __syncthreads();

    for (int ch = 0; ch < 8; ++ch) {
        int cur = ch & 1;
        // issue next chunk's loads early (latency hides under compute)
        if (ch < 7) {
            v0 = *(const f32x4*)(g0 + (size_t)(ch + 1) * gstride);
            v1 = *(const f32x4*)(g1 + (size_t)(ch + 1) * gstride);
        }
        // compute current chunk from LDS
        float a0 = 0.f, a1 = 0.f;
        const float* sb = stage[cur] + r * 128;
#pragma unroll
        for (int j4 = 0; j4 < 8; ++j4) {
            f32x4 a = *(const f32x4*)(sb + ((q << 3) | (j4 ^ sw)) * 4);
            a0 += a.x * kr0[j4].x + a.y * kr0[j4].y + a.z * kr0[j4].z + a.w * kr0[j4].w;
            a1 += a.x * kr1[j4].x + a.y * kr1[j4].y + a.z * kr1[j4].z + a.w * kr1[j4].w;
        }
        a0 += __shfl_xor(a0, 1); a0 += __shfl_xor(a0, 2);
        a1 += __shfl_xor(a1, 1); a1 += __shfl_xor(a1, 2);
        if (q == 0) {
            int nn = r & 7, mm = 2 * ch + (r >> 3);
            tb[(2 * bp)     * 128 + nn * 16 + mm] = f2bf(a0);
            tb[(2 * bp + 1) * 128 + nn * 16 + mm] = f2bf(a1);
        }
        // write next chunk to the other buffer (after compute: write-late)
        if (ch < 7) {
            *(f32x4*)(stage[cur ^ 1] + so0) = v0;
            *(f32x4*)(stage[cur ^ 1] + so1) = v1;
        }
        __syncthreads();
    }

    // coalesced output: 64 (b,n') pairs x 32B (16 m), 8B per thread
    int pair = t >> 2, sub = t & 3;
    int bw = pair >> 3, np = pair & 7;
    u16x4 v = *(const u16x4*)(tb + bw * 128 + np * 16 + sub * 4);
    *(u16x4*)(outp + ((size_t)(bw * NTOT + n0 + np)) * MTOT + m0 + sub * 4) = v;
}

// ---------------------------------------------------------------------------
// fc1: h[b][s][l] = relu( sum_d x[b][s][d] * D[b][d][l] )  -> bf16
// tile: M=32 (s), N=128 (all l), K-loop 1024 step 64. grid = 8*64 = 512
// ---------------------------------------------------------------------------
__global__ __launch_bounds__(256) void fc1(const float* __restrict__ x,
                                           const u16* __restrict__ DgT,
                                           u16* __restrict__ h) {
    __shared__ u16 As[32][72];
    __shared__ u16 Bs[128][72];
    int t = threadIdx.x;
    int bid = blockIdx.x;
    int b = bid >> 6, st = bid & 63;
    int s0 = st * 32;
    const float* xb = x + ((size_t)b * SEQ + s0) * IN_DIM;
    const u16* Db = DgT + (size_t)b * LOW * IN_DIM;

    int w = t >> 6, lane = t & 63;
    int wm = w >> 1, wn = w & 1;
    int lr = lane & 15, hi = lane >> 4;

    f32x4 acc[4];
#pragma unroll
    for (int nf = 0; nf < 4; ++nf) acc[nf] = (f32x4){0.f, 0.f, 0.f, 0.f};

    int ar = t >> 3, ac = t & 7;
    int brt = t >> 3, bc = t & 7;

    for (int kt = 0; kt < IN_DIM / 64; ++kt) {
        int k0 = kt * 64;
#pragma unroll
        for (int i = 0; i < 2; ++i) {
            float4 v = *(const float4*)(xb + (size_t)ar * IN_DIM + k0 + ac * 4 + i * 32);
            u16x4 o;
            o.x = f2bf(v.x); o.y = f2bf(v.y); o.z = f2bf(v.z); o.w = f2bf(v.w);
            *(u16x4*)(&As[ar][ac * 4 + i * 32]) = o;
        }
#pragma unroll
        for (int i = 0; i < 4; ++i) {
            int row = brt + 32 * i;
            bf16x8 v = *(const bf16x8*)(Db + (size_t)row * IN_DIM + k0 + bc * 8);
            *(bf16x8*)(&Bs[row][bc * 8]) = v;
        }
        __syncthreads();
#pragma unroll
        for (int ks = 0; ks < 2; ++ks) {
            int kk = ks * 32 + hi * 8;
            bf16x8 af = *(const bf16x8*)(&As[wm * 16 + lr][kk]);
#pragma unroll
            for (int nf = 0; nf < 4; ++nf) {
                bf16x8 bf = *(const bf16x8*)(&Bs[wn * 64 + nf * 16 + lr][kk]);
                acc[nf] = __builtin_amdgcn_mfma_f32_16x16x32_bf16(af, bf, acc[nf], 0, 0, 0);
            }
        }
        __syncthreads();
    }
    u16* hb = h + ((size_t)b * SEQ + s0) * LOW;
#pragma unroll
    for (int nf = 0; nf < 4; ++nf) {
        int col = wn * 64 + nf * 16 + lr;
#pragma unroll
        for (int j = 0; j < 4; ++j) {
            int rrow = wm * 16 + hi * 4 + j;
            hb[(size_t)rrow * LOW + col] = f2bf(fmaxf(acc[nf][j], 0.f));
        }
    }
}

// ---------------------------------------------------------------------------
// fc2: out[b][s][o] = sum_l h[b][s][l] * U[b][l][o]   (f32 out)
// tile: 128x128, K=128 staged once. grid = 8*16*8 = 1024
// ---------------------------------------------------------------------------
__global__ __launch_bounds__(256) void fc2(const u16* __restrict__ h,
                                           const u16* __restrict__ UgT,
                                           float* __restrict__ out) {
    __shared__ u16 As[128 * 128];
    __shared__ u16 Bs[128 * 128];
    int t = threadIdx.x;
    int bid = blockIdx.x;
    int b = bid >> 7, st = (bid >> 3) & 15, ot = bid & 7;
    int s0 = st * 128, o0 = ot * 128;
    const u16* hb = h + ((size_t)b * SEQ + s0) * LOW;
    const u16* Ub = UgT + ((size_t)b * OUT_DIM + o0) * LOW;

#pragma unroll
    for (int i = 0; i < 8; ++i) {
        int ch = i * 256 + t;
        int row = ch >> 4, c = ch & 15;
        int swc = c ^ (row & 7);
        *(bf16x8*)(As + row * 128 + swc * 8) = *(const bf16x8*)(hb + (size_t)ch * 8);
        *(bf16x8*)(Bs + row * 128 + swc * 8) = *(const bf16x8*)(Ub + (size_t)ch * 8);
    }
    __syncthreads();

    int w = t >> 6, lane = t & 63;
    int wm = w >> 1, wn = w & 1;
    int lr = lane & 15, lkc = (lane >> 4);

    f32x4 acc[4][4];
#pragma unroll
    for (int mf = 0; mf < 4; ++mf)
#pragma unroll
        for (int nf = 0; nf < 4; ++nf)
            acc[mf][nf] = (f32x4){0.f, 0.f, 0.f, 0.f};

#pragma unroll
    for (int ks = 0; ks < 4; ++ks) {
        bf16x8 af[4], bfr[4];
#pragma unroll
        for (int mf = 0; mf < 4; ++mf) {
            int row = wm * 64 + mf * 16 + lr;
            int swc = (ks * 4 + lkc) ^ (row & 7);
            af[mf] = *(const bf16x8*)(As + row * 128 + swc * 8);
        }
#pragma unroll
        for (int nf = 0; nf < 4; ++nf) {
            int row = wn * 64 + nf * 16 + lr;
            int swc = (ks * 4 + lkc) ^ (row & 7);
            bfr[nf] = *(const bf16x8*)(Bs + row * 128 + swc * 8);
        }
#pragma unroll
        for (int mf = 0; mf < 4; ++mf)
#pragma unroll
            for (int nf = 0; nf < 4; ++nf)
                acc[mf][nf] = __builtin_amdgcn_mfma_f32_16x16x32_bf16(
                    af[mf], bfr[nf], acc[mf][nf], 0, 0, 0);
    }

    float* ob = out + ((size_t)b * SEQ + s0) * OUT_DIM + o0;
#pragma unroll
    for (int mf = 0; mf < 4; ++mf)
#pragma unroll
        for (int nf = 0; nf < 4; ++nf) {
            int col = wn * 64 + nf * 16 + lr;
#pragma unroll
            for (int j = 0; j < 4; ++j) {
                int rrow = wm * 64 + mf * 16 + (lane >> 4) * 4 + j;
                ob[(size_t)rrow * OUT_DIM + col] = acc[mf][nf][j];
            }
        }
}

extern "C" void kernel_launch(void* const* d_in, const int* in_sizes, int n_in,
                              void* d_out, int out_size, void* d_ws, size_t ws_size,
                              hipStream_t stream) {
    const float* x  = (const float*)d_in[0];
    const float* kv = (const float*)d_in[1];
    const float* Dm = (const float*)d_in[2];
    const float* Um = (const float*)d_in[3];
    float* out = (float*)d_out;

    u16* DgT = (u16*)d_ws;                                   // 2 MB
    u16* UgT = DgT + (size_t)BATCH * LOW * IN_DIM;           // 2 MB
    u16* hbuf = UgT + (size_t)BATCH * OUT_DIM * LOW;         // 4 MB

    gen_w<<<dim3(2048), dim3(256), 0, stream>>>(Dm, Um, kv, DgT, UgT);
    fc1<<<dim3(512), dim3(256), 0, stream>>>(x, DgT, hbuf);
    fc2<<<dim3(1024), dim3(256), 0, stream>>>(hbuf, UgT, out);
}

// Round 5
// 71.388 us; speedup vs baseline: 1.0068x; 1.0068x over previous
//
#include <hip/hip_runtime.h>
#include <hip/hip_bf16.h>
#include <stdint.h>

#define IN_DIM  1024
#define LOW     128
#define OUT_DIM 1024
#define BATCH   8
#define SEQ     2048

typedef unsigned short u16;
typedef short bf16x8 __attribute__((ext_vector_type(8)));
typedef unsigned short u16x4 __attribute__((ext_vector_type(4)));
typedef float f32x4 __attribute__((ext_vector_type(4)));

__device__ __forceinline__ u16 f2bf(float f) {
    union { float f; uint32_t u; } v;
    v.f = f;
    uint32_t u = v.u;
    return (u16)((u + 0x7fffu + ((u >> 16) & 1u)) >> 16);
}

__device__ __forceinline__ void gload16(const float* g, float* l) {
    __builtin_amdgcn_global_load_lds(
        (const __attribute__((address_space(1))) void*)g,
        (__attribute__((address_space(3))) void*)l, 16, 0, 0);
}

// ---------------------------------------------------------------------------
// gen_w v4: MFMA + global_load_lds, compiler-managed sync ONLY (m97 structure).
//   D half (bid<512):  DgT[b][l][d] = dot(Dm[d*128+l][:], k[b][:])
//   U half (bid>=512): UgT[b][o][l] = dot(Um[l*1024+o][:], k[b][:])
// Skinny GEMM C[p][b] = M[p][:] @ k[b][:]^T via mfma_f32_16x16x32_bf16.
// Block = 256 rows (32 m x 8 n), 4 chunks of 64 rows (32KB f32), double-buf.
// Per iter: __syncthreads() (drains vmcnt -> chunk c landed, prev reads done)
//           -> issue chunk c+1 glds into other buffer -> compute chunk c.
// All 4 waves compute (wave w owns rows [w*16, w*16+16) of the chunk).
// Staging: glds dwordx4, linear LDS dest (t*16B + i*4KB), pre-swizzled
// global source (chunk ^= row&7) per m173; read side XORs the same swizzle.
// LDS 68KB -> 2 blocks/CU. grid 1024.
// ---------------------------------------------------------------------------
__global__ __launch_bounds__(256) void gen_w(const float* __restrict__ Dm,
                                             const float* __restrict__ Um,
                                             const float* __restrict__ kv,
                                             u16* __restrict__ DgT,
                                             u16* __restrict__ UgT) {
    __shared__ float sbuf[2][64 * 128];   // 2 x 32KB staging
    __shared__ u16 tb[8 * 8 * 32];        // 4KB transpose buffer

    int t = threadIdx.x;
    int bid = blockIdx.x;
    bool isU = bid >= 512;
    int rb = isU ? (bid - 512) : bid;
    const float* src = isU ? Um : Dm;
    u16* outp = isU ? UgT : DgT;
    int NTOT = isU ? 1024 : 128;   // p row-stride (minor dim)
    int MTOT = isU ? 128 : 1024;   // output contiguous-run dim
    int sh = isU ? 7 : 4;
    int m0 = (rb >> sh) * 32;
    int n0 = (rb & ((1 << sh) - 1)) * 8;

    // staging map: instr i of chunk c -> LDS row 8i+g8, 16B-chunk (t&31);
    // global row (m = m0+8c+i, n = n0+g8), source chunk pre-XOR'd with g8.
    int g8 = t >> 5;                       // == LDS row & 7
    int srcChunk = (t & 31) ^ g8;
    const float* gbase = src + ((size_t)m0 * NTOT + n0 + g8) * 128 + srcChunk * 4;
    size_t mstep = (size_t)NTOT * 128;     // floats per m step

    int lane = t & 63, w = t >> 6;
    int bb = lane & 15;                    // A-row / C-col index (batch for C)
    int hi = lane >> 4;                    // k-subgroup
    int rsw = lane & 7;                    // read swizzle == chunk-row & 7

    // B-fragments: bf16(k), constant (16 VGPRs); cols 8..15 zero
    bf16x8 bfrag[4];
#pragma unroll
    for (int ks = 0; ks < 4; ++ks)
#pragma unroll
        for (int j = 0; j < 8; ++j) {
            float kvf = (bb < 8) ? kv[bb * LOW + ks * 32 + hi * 8 + j] : 0.f;
            bfrag[ks][j] = (short)f2bf(kvf);
        }

    // prologue: stage chunk 0 (m = m0+0..7)
    {
        float* l0 = &sbuf[0][t * 4];
#pragma unroll
        for (int i = 0; i < 8; ++i)
            gload16(gbase + (size_t)i * mstep, l0 + i * 1024);
    }

    for (int c = 0; c < 4; ++c) {
        __syncthreads();   // drains vmcnt(0)+lgkmcnt(0): chunk c landed,
                           // and all waves' reads of buf[c&1] (from iter c-2's
                           // writes / iter c-1's compute) are complete.
        if (c < 3) {
            float* ln = &sbuf[(c + 1) & 1][t * 4];
            const float* gn = gbase + (size_t)(8 * (c + 1)) * mstep;
#pragma unroll
            for (int i = 0; i < 8; ++i)
                gload16(gn + (size_t)i * mstep, ln + i * 1024);
        }
        // compute chunk c: wave w owns chunk rows [w*16, w*16+16)
        const float* rowp = sbuf[c & 1] + (w * 16 + bb) * 128;
        f32x4 acc = (f32x4){0.f, 0.f, 0.f, 0.f};
#pragma unroll
        for (int ks = 0; ks < 4; ++ks) {
            int c0 = ks * 8 + hi * 2;
            f32x4 v0 = *(const f32x4*)(rowp + ((c0)     ^ rsw) * 4);
            f32x4 v1 = *(const f32x4*)(rowp + ((c0 + 1) ^ rsw) * 4);
            bf16x8 afr;
            afr[0] = (short)f2bf(v0.x); afr[1] = (short)f2bf(v0.y);
            afr[2] = (short)f2bf(v0.z); afr[3] = (short)f2bf(v0.w);
            afr[4] = (short)f2bf(v1.x); afr[5] = (short)f2bf(v1.y);
            afr[6] = (short)f2bf(v1.z); afr[7] = (short)f2bf(v1.w);
            acc = __builtin_amdgcn_mfma_f32_16x16x32_bf16(afr, bfrag[ks], acc, 0, 0, 0);
        }
        // C/D layout: col=lane&15 (=batch bb), row=hi*4+j (=tile row r)
        if (bb < 8) {
#pragma unroll
            for (int j = 0; j < 4; ++j) {
                int r = hi * 4 + j;                  // tile row 0..15
                int mm = c * 8 + w * 2 + (r >> 3);   // block-local m 0..31
                tb[bb * 256 + (r & 7) * 32 + mm] = f2bf(acc[j]);
            }
        }
    }
    __syncthreads();   // tb writes visible to all

    // coalesced output: 64 chunks (b,n') x 64B (32 m)
    int c64 = t >> 2, q4 = t & 3;
    int bw = c64 >> 3, np = c64 & 7;
    bf16x8 v = *(const bf16x8*)(tb + bw * 256 + np * 32 + q4 * 8);
    *(bf16x8*)(outp + ((size_t)(bw * NTOT + n0 + np)) * MTOT + m0 + q4 * 8) = v;
}

// ---------------------------------------------------------------------------
// fc1: h[b][s][l] = relu( sum_d x[b][s][d] * D[b][d][l] )  -> bf16
// tile: M=32 (s), N=128 (all l), K-loop 1024 step 64. grid = 8*64 = 512
// ---------------------------------------------------------------------------
__global__ __launch_bounds__(256) void fc1(const float* __restrict__ x,
                                           const u16* __restrict__ DgT,
                                           u16* __restrict__ h) {
    __shared__ u16 As[32][72];
    __shared__ u16 Bs[128][72];
    int t = threadIdx.x;
    int bid = blockIdx.x;
    int b = bid >> 6, st = bid & 63;
    int s0 = st * 32;
    const float* xb = x + ((size_t)b * SEQ + s0) * IN_DIM;
    const u16* Db = DgT + (size_t)b * LOW * IN_DIM;

    int w = t >> 6, lane = t & 63;
    int wm = w >> 1, wn = w & 1;
    int lr = lane & 15, hi = lane >> 4;

    f32x4 acc[4];
#pragma unroll
    for (int nf = 0; nf < 4; ++nf) acc[nf] = (f32x4){0.f, 0.f, 0.f, 0.f};

    int ar = t >> 3, ac = t & 7;
    int brt = t >> 3, bc = t & 7;

    for (int kt = 0; kt < IN_DIM / 64; ++kt) {
        int k0 = kt * 64;
#pragma unroll
        for (int i = 0; i < 2; ++i) {
            float4 v = *(const float4*)(xb + (size_t)ar * IN_DIM + k0 + ac * 4 + i * 32);
            u16x4 o;
            o.x = f2bf(v.x); o.y = f2bf(v.y); o.z = f2bf(v.z); o.w = f2bf(v.w);
            *(u16x4*)(&As[ar][ac * 4 + i * 32]) = o;
        }
#pragma unroll
        for (int i = 0; i < 4; ++i) {
            int row = brt + 32 * i;
            bf16x8 v = *(const bf16x8*)(Db + (size_t)row * IN_DIM + k0 + bc * 8);
            *(bf16x8*)(&Bs[row][bc * 8]) = v;
        }
        __syncthreads();
#pragma unroll
        for (int ks = 0; ks < 2; ++ks) {
            int kk = ks * 32 + hi * 8;
            bf16x8 af = *(const bf16x8*)(&As[wm * 16 + lr][kk]);
#pragma unroll
            for (int nf = 0; nf < 4; ++nf) {
                bf16x8 bf = *(const bf16x8*)(&Bs[wn * 64 + nf * 16 + lr][kk]);
                acc[nf] = __builtin_amdgcn_mfma_f32_16x16x32_bf16(af, bf, acc[nf], 0, 0, 0);
            }
        }
        __syncthreads();
    }
    u16* hb = h + ((size_t)b * SEQ + s0) * LOW;
#pragma unroll
    for (int nf = 0; nf < 4; ++nf) {
        int col = wn * 64 + nf * 16 + lr;
#pragma unroll
        for (int j = 0; j < 4; ++j) {
            int rrow = wm * 16 + hi * 4 + j;
            hb[(size_t)rrow * LOW + col] = f2bf(fmaxf(acc[nf][j], 0.f));
        }
    }
}

// ---------------------------------------------------------------------------
// fc2: out[b][s][o] = sum_l h[b][s][l] * U[b][l][o]   (f32 out)
// tile: 128x128, K=128 staged once. grid = 8*16*8 = 1024
// ---------------------------------------------------------------------------
__global__ __launch_bounds__(256) void fc2(const u16* __restrict__ h,
                                           const u16* __restrict__ UgT,
                                           float* __restrict__ out) {
    __shared__ u16 As[128 * 128];
    __shared__ u16 Bs[128 * 128];
    int t = threadIdx.x;
    int bid = blockIdx.x;
    int b = bid >> 7, st = (bid >> 3) & 15, ot = bid & 7;
    int s0 = st * 128, o0 = ot * 128;
    const u16* hb = h + ((size_t)b * SEQ + s0) * LOW;
    const u16* Ub = UgT + ((size_t)b * OUT_DIM + o0) * LOW;

#pragma unroll
    for (int i = 0; i < 8; ++i) {
        int ch = i * 256 + t;
        int row = ch >> 4, c = ch & 15;
        int swc = c ^ (row & 7);
        *(bf16x8*)(As + row * 128 + swc * 8) = *(const bf16x8*)(hb + (size_t)ch * 8);
        *(bf16x8*)(Bs + row * 128 + swc * 8) = *(const bf16x8*)(Ub + (size_t)ch * 8);
    }
    __syncthreads();

    int w = t >> 6, lane = t & 63;
    int wm = w >> 1, wn = w & 1;
    int lr = lane & 15, lkc = (lane >> 4);

    f32x4 acc[4][4];
#pragma unroll
    for (int mf = 0; mf < 4; ++mf)
#pragma unroll
        for (int nf = 0; nf < 4; ++nf)
            acc[mf][nf] = (f32x4){0.f, 0.f, 0.f, 0.f};

#pragma unroll
    for (int ks = 0; ks < 4; ++ks) {
        bf16x8 af[4], bfr[4];
#pragma unroll
        for (int mf = 0; mf < 4; ++mf) {
            int row = wm * 64 + mf * 16 + lr;
            int swc = (ks * 4 + lkc) ^ (row & 7);
            af[mf] = *(const bf16x8*)(As + row * 128 + swc * 8);
        }
#pragma unroll
        for (int nf = 0; nf < 4; ++nf) {
            int row = wn * 64 + nf * 16 + lr;
            int swc = (ks * 4 + lkc) ^ (row & 7);
            bfr[nf] = *(const bf16x8*)(Bs + row * 128 + swc * 8);
        }
#pragma unroll
        for (int mf = 0; mf < 4; ++mf)
#pragma unroll
            for (int nf = 0; nf < 4; ++nf)
                acc[mf][nf] = __builtin_amdgcn_mfma_f32_16x16x32_bf16(
                    af[mf], bfr[nf], acc[mf][nf], 0, 0, 0);
    }

    float* ob = out + ((size_t)b * SEQ + s0) * OUT_DIM + o0;
#pragma unroll
    for (int mf = 0; mf < 4; ++mf)
#pragma unroll
        for (int nf = 0; nf < 4; ++nf) {
            int col = wn * 64 + nf * 16 + lr;
#pragma unroll
            for (int j = 0; j < 4; ++j) {
                int rrow = wm * 64 + mf * 16 + (lane >> 4) * 4 + j;
                ob[(size_t)rrow * OUT_DIM + col] = acc[mf][nf][j];
            }
        }
}

extern "C" void kernel_launch(void* const* d_in, const int* in_sizes, int n_in,
                              void* d_out, int out_size, void* d_ws, size_t ws_size,
                              hipStream_t stream) {
    const float* x  = (const float*)d_in[0];
    const float* kv = (const float*)d_in[1];
    const float* Dm = (const float*)d_in[2];
    const float* Um = (const float*)d_in[3];
    float* out = (float*)d_out;

    u16* DgT = (u16*)d_ws;                                   // 2 MB
    u16* UgT = DgT + (size_t)BATCH * LOW * IN_DIM;           // 2 MB
    u16* hbuf = UgT + (size_t)BATCH * OUT_DIM * LOW;         // 4 MB

    gen_w<<<dim3(1024), dim3(256), 0, stream>>>(Dm, Um, kv, DgT, UgT);
    fc1<<<dim3(512), dim3(256), 0, stream>>>(x, DgT, hbuf);
    fc2<<<dim3(1024), dim3(256), 0, stream>>>(hbuf, UgT, out);
}